// Round 17
// baseline (413.738 us; speedup 1.0000x reference)
//
#include <hip/hip_runtime.h>

#define NB 4
#define C 96
#define HH 256
#define WW 256
#define NPIX (HH*WW)
#define HEADS 4
#define CH 24

// ---- kconv tiling: interior 16 wide x 14 tall, halo 18x16 ----
#define NTX2 16
#define NTY2 19
#define NTILES (NTX2*NTY2)
#define YP 296      // fallback Ysh pitch
#define QP 264      // fallback qS/kT pitch
#define VP 104      // fallback vS pitch
#define KSPLIT 128
#define YR 24       // kconv Ysh row pitch (shorts)
#define YC 392      // kconv Ysh channel stride (shorts)
#define XTP 76      // k0t LDS pitch (shorts)
#define VCH 40      // kvm vS pitch (shorts)

// ---- kvm tiling: interior 32 wide x 8 tall (exact), halo 34x10 ----
#define VHP2 340    // halo pixels
#define VXP2 40     // Ysh row pitch (shorts)
#define VYC2 400    // Ysh channel stride (10*40)
#define NTV2 256    // 8 x 32 tiles

#define WS_SUMSQ_Q 0
#define WS_SUMSQ_K (WS_SUMSQ_Q + NB*C)
#define WS_GRAM    (WS_SUMSQ_K + NB*C)
#define WS_MS      (WS_GRAM + NB*HEADS*CH*CH)
#define WS_MSH     (WS_MS + NB*C*C)

// shared xt region
#define XT_OFF_BYTES ((size_t)335872)
#define XT_BYTES   ((size_t)2*NB*NPIX*96*2)

// ---- fallback (r4) layout ----
#define F_PSQ_OFF   (XT_OFF_BYTES + XT_BYTES)
#define F_PSQ_BYTES ((size_t)NTILES*NB*192*4)
#define F_PG_OFF    (F_PSQ_OFF + F_PSQ_BYTES)
#define F_PG_BYTES  ((size_t)NTILES*NB*HEADS*1024*4)
#define F_MB_OFF    (F_PG_OFF + F_PG_BYTES)
#define F_MB_BYTES  ((size_t)2*NB*96*96*2)
#define F_WS_NEED   (F_MB_OFF + F_MB_BYTES)

// ---- main layout ----
#define QK_OFF    (XT_OFF_BYTES + XT_BYTES)
#define QK_BYTES  ((size_t)2*NB*96*NPIX*2)
#define PG_OFF    (QK_OFF + QK_BYTES)
#define PG_BYTES  ((size_t)KSPLIT*NB*9216*4)
#define PSQ_OFF   (PG_OFF + PG_BYTES)
#define PSQ_BYTES ((size_t)4*NTILES*NB*48*4)
#define MB_OFF    (PSQ_OFF + PSQ_BYTES)
#define MB_BYTES  ((size_t)2*NB*96*96*2)
#define WB_OFF    (MB_OFF + MB_BYTES)
#define WB_BYTES  ((size_t)384*96*2)
#define WS_NEED3  (WB_OFF + WB_BYTES)

typedef short short8 __attribute__((ext_vector_type(8)));
typedef float f32x4 __attribute__((ext_vector_type(4)));
typedef float f32x16 __attribute__((ext_vector_type(16)));

__device__ __forceinline__ unsigned short f2b(float f){
  unsigned u = __float_as_uint(f);
  unsigned r = u + 0x7FFFu + ((u >> 16) & 1u);
  return (unsigned short)(r >> 16);
}
__device__ __forceinline__ float b2f(unsigned short s){
  return __uint_as_float(((unsigned)s) << 16);
}
__device__ __forceinline__ unsigned cvtpk(float lo, float hi){
  unsigned r;
  asm("v_cvt_pk_bf16_f32 %0, %1, %2" : "=v"(r) : "v"(lo), "v"(hi));
  return r;
}
__device__ __forceinline__ short8 pack8(float4 a, float4 b){
  short8 r;
  r[0]=(short)f2b(a.x); r[1]=(short)f2b(a.y); r[2]=(short)f2b(a.z); r[3]=(short)f2b(a.w);
  r[4]=(short)f2b(b.x); r[5]=(short)f2b(b.y); r[6]=(short)f2b(b.z); r[7]=(short)f2b(b.w);
  return r;
}

// ============================ K0: fp32 [c][gy][gx] -> bf16 [px][c]; cm=1: px = gx*HH+gy ============================
__global__ __launch_bounds__(256) void k0t(
  const float* __restrict__ content, const float* __restrict__ style,
  unsigned short* __restrict__ xt, int cm)
{
  __shared__ unsigned short Xt[96*XTP];
  const int t = threadIdx.x;
  const int n0 = blockIdx.x * 64;
  const int b = blockIdx.y, src = blockIdx.z;
  const int gyr = n0 >> 8, gxb = n0 & 255;
  const float* in = (src ? style : content) + (size_t)b*C*NPIX;
  #pragma unroll
  for (int i = 0; i < 6; ++i){
    int s = i*256 + t;
    int r = s >> 4, c4 = s & 15;
    float4 f = *(const float4*)(in + (size_t)r*NPIX + n0 + c4*4);
    unsigned lo = ((unsigned)f2b(f.y) << 16) | f2b(f.x);
    unsigned hi = ((unsigned)f2b(f.w) << 16) | f2b(f.z);
    *(uint2*)&Xt[r*XTP + c4*4] = make_uint2(lo, hi);
  }
  __syncthreads();
  unsigned* dst = (unsigned*)(xt + ((size_t)src*NB + b)*NPIX*96);
  #pragma unroll
  for (int i = 0; i < 12; ++i){
    int s = i*256 + t;
    int j = s / 48, c2 = s - j*48;
    unsigned v = ((unsigned)Xt[(c2*2+1)*XTP + j] << 16) | Xt[(c2*2)*XTP + j];
    size_t np = cm ? ((size_t)(gxb + j)*HH + gyr) : (size_t)(n0 + j);
    dst[np*48 + c2] = v;
  }
}

// ============================ kwpack ============================
__global__ __launch_bounds__(256) void kwpack(
  const float* __restrict__ q_w, const float* __restrict__ kv_w,
  unsigned short* __restrict__ wb)
{
  int i = blockIdx.x*256 + threadIdx.x;
  if (i < 9216) wb[i] = f2b(q_w[i]);
  else if (i < 36864) wb[i] = f2b(kv_w[i - 9216]);
}

// ============================ kconv: q,k only. z: 0,1 q (content); 2,3 k (style) ============================
__global__ __launch_bounds__(512, 4) void kconv(
  const unsigned short* __restrict__ xt, const unsigned short* __restrict__ wb,
  const float* __restrict__ q_b, const float* __restrict__ qd_w, const float* __restrict__ qd_b,
  const float* __restrict__ kv_b, const float* __restrict__ kvd_w, const float* __restrict__ kvd_b,
  unsigned short* __restrict__ qk, float* __restrict__ psq)
{
  __shared__ unsigned short Ysh[48*YC];   // 37632 B
  __shared__ float red[48];
  const int t = threadIdx.x, lane = t & 63, w = t >> 6;
  const int tile = blockIdx.x, b = blockIdx.y, z = blockIdx.z;
  const int txx = tile & 15, tyy = tile >> 4;
  const int gx0 = txx*16, gy0 = tyy*14;
  const unsigned short* xsrc = xt + ((size_t)((z < 2 ? 0 : 1)*NB + b))*NPIX*96;
  const int wrow0 = (z < 2) ? z*48 : 96 + (z-2)*48;
  const float* cb  = (z<2) ? q_b  + z*48           : kv_b  + (size_t)(z-2)*48;
  const float* dww = (z<2) ? qd_w + (size_t)z*48*9 : kvd_w + (size_t)(z-2)*48*9;
  const float* dwb = (z<2) ? qd_b + z*48           : kvd_b + (size_t)(z-2)*48;
  unsigned short* dst0 = (z < 2)
      ? qk + ((size_t)(0*NB + b)*96 + (size_t)z*48)*NPIX
      : qk + ((size_t)(1*NB + b)*96 + (size_t)(z-2)*48)*NPIX;

  if (t < 48) red[t] = 0.f;

  // persistent halo fragments — xt column-major
  const int hy = lane & 15, khalf = lane >> 4;
  const int gyh = gy0 - 1 + hy;
  short8 xf[3][3]; bool imv[3];
  const int np = (w < 2) ? 3 : 2;
  #pragma unroll
  for (int i = 0; i < 3; ++i){
    if (i >= np) break;
    int pt = w + i*8;
    int gx = gx0 - 1 + pt;
    bool im = (gx>=0) && (gx<WW) && (gyh>=0) && (gyh<HH);
    imv[i] = im;
    const unsigned short* xp = xsrc + (size_t)(im ? (gx*HH + gyh) : 0)*96 + khalf*8;
    short8 zz = {};
    #pragma unroll
    for (int kk = 0; kk < 3; ++kk){
      short8 v = *(const short8*)(xp + kk*32);
      xf[i][kk] = im ? v : zz;
    }
  }

  // conv1x1: 48 output rows over halo -> Ysh [ch][hy][pt]
  #pragma unroll 1
  for (int mi = 0; mi < 3; ++mi){
    const unsigned short* wp = wb + (size_t)(wrow0 + mi*16 + hy)*96 + khalf*8;
    short8 a0 = *(const short8*)(wp);
    short8 a1 = *(const short8*)(wp + 32);
    short8 a2 = *(const short8*)(wp + 64);
    float4 bv = *(const float4*)&cb[mi*16 + khalf*4];
    #pragma unroll
    for (int i = 0; i < 3; ++i){
      if (i >= np) break;
      int pt = w + i*8;
      f32x4 acc = {bv.x, bv.y, bv.z, bv.w};
      acc = __builtin_amdgcn_mfma_f32_16x16x32_bf16(a0, xf[i][0], acc, 0,0,0);
      acc = __builtin_amdgcn_mfma_f32_16x16x32_bf16(a1, xf[i][1], acc, 0,0,0);
      acc = __builtin_amdgcn_mfma_f32_16x16x32_bf16(a2, xf[i][2], acc, 0,0,0);
      #pragma unroll
      for (int r = 0; r < 4; ++r){
        int ch = mi*16 + khalf*4 + r;
        Ysh[ch*YC + hy*YR + pt] = imv[i] ? f2b(acc[r]) : (unsigned short)0;
      }
    }
  }
  __syncthreads();

  // dw 3x3, wave-balanced
  for (int sl = lane; sl < 84; sl += 64){
    int slot = w*84 + sl;                 // 0..671
    int c = slot / 14, py = slot - (slot/14)*14;
    int gy = gy0 + py;
    if (gy < HH){
      const float* wd = dww + (size_t)c*9;
      float w00=wd[0],w01=wd[1],w02=wd[2],w10=wd[3],w11=wd[4],w12=wd[5],w20=wd[6],w21=wd[7],w22=wd[8];
      float bb = dwb[c];
      const unsigned short* yb = &Ysh[c*YC + py*YR];
      float o[16];
      #pragma unroll
      for (int half = 0; half < 2; ++half){
        float u[3][10];
        #pragma unroll
        for (int uu = 0; uu < 3; ++uu){
          const unsigned short* rp = yb + uu*YR + half*8;
          short8 s = *(const short8*)rp;
          unsigned ex = *(const unsigned*)(rp + 8);
          #pragma unroll
          for (int j = 0; j < 8; ++j) u[uu][j] = b2f((unsigned short)s[j]);
          u[uu][8] = b2f((unsigned short)(ex & 0xffffu));
          u[uu][9] = b2f((unsigned short)(ex >> 16));
        }
        #pragma unroll
        for (int j = 0; j < 8; ++j){
          float s = bb;
          s = fmaf(w00,u[0][j],s); s = fmaf(w01,u[0][j+1],s); s = fmaf(w02,u[0][j+2],s);
          s = fmaf(w10,u[1][j],s); s = fmaf(w11,u[1][j+1],s); s = fmaf(w12,u[1][j+2],s);
          s = fmaf(w20,u[2][j],s); s = fmaf(w21,u[2][j+1],s); s = fmaf(w22,u[2][j+2],s);
          o[half*8 + j] = s;
        }
      }
      float sq = 0.f;
      #pragma unroll
      for (int j = 0; j < 16; ++j) sq = fmaf(o[j], o[j], sq);
      atomicAdd(&red[c], sq);
      unsigned vvp[8];
      #pragma unroll
      for (int jj = 0; jj < 8; ++jj) vvp[jj] = cvtpk(o[2*jj], o[2*jj+1]);
      unsigned short* qp = dst0 + (size_t)c*NPIX + (size_t)gy*WW + gx0;
      *(uint4*)qp       = make_uint4(vvp[0], vvp[1], vvp[2], vvp[3]);
      *(uint4*)(qp + 8) = make_uint4(vvp[4], vvp[5], vvp[6], vvp[7]);
    }
  }
  __syncthreads();
  if (t < 48)
    psq[((size_t)(z*NTILES + tile)*NB + b)*48 + t] = red[t];
}

// ============================ kgram: partial-K Gram ============================
__global__ __launch_bounds__(384) void kgram(
  const unsigned short* __restrict__ qk, float* __restrict__ pg)
{
  const int t = threadIdx.x, lane = t & 63, wv = t >> 6;
  const int ks = blockIdx.x, b = blockIdx.y;
  const int n0 = ks * (NPIX / KSPLIT);
  const unsigned short* qb = qk + ((size_t)(0*NB + b)*96)*NPIX;
  const unsigned short* kb = qk + ((size_t)(1*NB + b)*96)*NPIX;
  f32x4 acc[6];
  #pragma unroll
  for (int i = 0; i < 6; ++i) acc[i] = (f32x4){0.f,0.f,0.f,0.f};
  #pragma unroll 1
  for (int st = 0; st < (NPIX/KSPLIT)/32; ++st){
    int off = n0 + st*32 + (lane>>4)*8;
    short8 bf = *(const short8*)(kb + (size_t)(wv*16 + (lane&15))*NPIX + off);
    #pragma unroll
    for (int ci = 0; ci < 6; ++ci){
      short8 af = *(const short8*)(qb + (size_t)(ci*16 + (lane&15))*NPIX + off);
      acc[ci] = __builtin_amdgcn_mfma_f32_16x16x32_bf16(af, bf, acc[ci], 0,0,0);
    }
  }
  float* dst = pg + ((size_t)ks*NB + b)*9216;
  #pragma unroll
  for (int ci = 0; ci < 6; ++ci){
    #pragma unroll
    for (int r = 0; r < 4; ++r)
      dst[(ci*6 + wv)*256 + ((lane>>4)*4 + r)*16 + (lane&15)] = acc[ci][r];
  }
}

// ============================ kgredN ============================
__global__ __launch_bounds__(256) void kgredN(
  const float* __restrict__ pg, const float* __restrict__ psq, float* __restrict__ ws)
{
  const int b = blockIdx.x, by = blockIdx.y, t = threadIdx.x;
  if (by < 36){
    int ci = by / 6;
    int qrow = ci*16 + (t >> 4), krow = (by - ci*6)*16 + (t & 15);
    float s = 0.f;
    for (int ks = 0; ks < KSPLIT; ++ks)
      s += pg[((size_t)ks*NB + b)*9216 + by*256 + t];
    int h = qrow / CH;
    if (krow / CH == h)
      ws[WS_GRAM + ((size_t)(b*HEADS + h)*CH + (qrow % CH))*CH + (krow % CH)] = s;
  } else {
    if (t < 192){
      int src = t / 96, c = t - (t/96)*96;
      int zz = src*2 + (c/48), cc = c - (c/48)*48;
      float s = 0.f;
      for (int tile = 0; tile < NTILES; ++tile)
        s += psq[((size_t)(zz*NTILES + tile)*NB + b)*48 + cc];
      ws[(src ? WS_SUMSQ_K : WS_SUMSQ_Q) + b*C + c] = s;
    }
  }
}

// ============================ k2: softmax + M matrices ============================
__global__ void k2_attn(
  const float* __restrict__ temp,
  const float* __restrict__ ps_w, const float* __restrict__ psh_w,
  float* __restrict__ ws, unsigned short* __restrict__ mb)
{
  const int b = blockIdx.x;
  const int t = threadIdx.x;
  __shared__ float attn[C * CH];
  __shared__ float nq[C], nk[C];
  if (t < C){
    nq[t] = fmaxf(sqrtf(ws[WS_SUMSQ_Q + b * C + t]), 1e-12f);
    nk[t] = fmaxf(sqrtf(ws[WS_SUMSQ_K + b * C + t]), 1e-12f);
  }
  __syncthreads();
  if (t < C){
    int h = t / CH;
    const float* g = ws + WS_GRAM + (((size_t)b * HEADS + h) * CH + (t % CH)) * CH;
    float tp = temp[h];
    float row[CH];
    float mx = -3.4e38f;
    #pragma unroll
    for (int d = 0; d < CH; ++d){
      row[d] = g[d] / (nq[t] * nk[h * CH + d]) * tp;
      mx = fmaxf(mx, row[d]);
    }
    float s = 0.f;
    #pragma unroll
    for (int d = 0; d < CH; ++d){ row[d] = expf(row[d] - mx); s += row[d]; }
    float inv = 1.f / s;
    #pragma unroll
    for (int d = 0; d < CH; ++d) attn[t * CH + d] = row[d] * inv;
  }
  __syncthreads();
  for (int idx = t; idx < C * C; idx += 256){
    int o = idx / C, dg = idx - o * C;
    int h = dg / CH, d = dg - h * CH;
    float s1 = 0.f, s2 = 0.f;
    #pragma unroll
    for (int c2 = 0; c2 < CH; ++c2){
      float a = attn[(h * CH + c2) * CH + d];
      s1 = fmaf(ps_w [(size_t)o * C + h * CH + c2], a, s1);
      s2 = fmaf(psh_w[(size_t)o * C + h * CH + c2], a, s2);
    }
    ws[WS_MS  + (size_t)b * C * C + idx] = s1;
    ws[WS_MSH + (size_t)b * C * C + idx] = s2;
    if (mb){
      mb[((size_t)0*NB + b)*9216 + idx] = f2b(s1);
      mb[((size_t)1*NB + b)*9216 + idx] = f2b(s2);
    }
  }
}

// ============================ kvm: fused v conv+dw+M-transform, 32x8 tiles ============================
// One block per (tile,b); loops z=0(scale),1(shift) internally reusing halo fragments.
__global__ __launch_bounds__(512, 4) void kvm(
  const unsigned short* __restrict__ xt, const unsigned short* __restrict__ wb,
  const float* __restrict__ kv_b, const float* __restrict__ kvd_w, const float* __restrict__ kvd_b,
  const unsigned short* __restrict__ mb,
  const float* __restrict__ ps_b, const float* __restrict__ psh_b,
  float* __restrict__ out)
{
  __shared__ unsigned short Ysh[32*VYC2];   // 25600 B
  __shared__ unsigned short vS[256*VCH];    // 20480 B
  const int t = threadIdx.x, lane = t & 63, w = t >> 6;
  const int tile = blockIdx.x, b = blockIdx.y;
  const int gx0 = (tile & 7)*32, gy0 = (tile >> 3)*8;
  const unsigned short* xsrc = xt + ((size_t)(NB + b))*NPIX*96;   // style

  // halo fragments: hp linearized down 10-px columns (matches column-major xt) — loaded ONCE
  const int pos = lane & 15, khalf = lane >> 4;
  const int npv = (w < 6) ? 3 : 2;     // 22 groups of 16 halo px over 8 waves
  short8 xf[3][3]; bool imv[3]; int hxv[3], hyv[3];
  #pragma unroll
  for (int i = 0; i < 3; ++i){
    if (i >= npv) break;
    int hp = (w + i*8)*16 + pos;       // 0..351 (valid < 340)
    int hx = hp / 10, hyy = hp - hx*10;
    hxv[i] = hx; hyv[i] = hyy;
    int gx = gx0 - 1 + hx, gy = gy0 - 1 + hyy;
    bool im = (hp < VHP2) && (gx>=0) && (gx<WW) && (gy>=0) && (gy<HH);
    imv[i] = im;
    const unsigned short* xp = xsrc + (size_t)(im ? (gx*HH + gy) : 0)*96 + khalf*8;
    short8 zz = {};
    #pragma unroll
    for (int kk = 0; kk < 3; ++kk){
      short8 v = *(const short8*)(xp + kk*32);
      xf[i][kk] = im ? v : zz;
    }
  }

  #pragma unroll 1
  for (int z = 0; z < 2; ++z){
    const float* bias = z ? psh_b : ps_b;
    f32x4 acc[6][2];
    #pragma unroll
    for (int mi = 0; mi < 6; ++mi){
      float4 bv = *(const float4*)&bias[mi*16 + khalf*4];
      acc[mi][0] = (f32x4){bv.x, bv.y, bv.z, bv.w};
      acc[mi][1] = acc[mi][0];
    }
    const unsigned short* mbp = mb + ((size_t)z*NB + b)*9216;

    #pragma unroll 1
    for (int ck = 0; ck < 3; ++ck){
      const int kvrow0 = 96 + z*96 + ck*32;   // row within kv (96..287)
      // conv1x1: 32 rows over halo -> Ysh [ch][hyy][hx]
      #pragma unroll 1
      for (int mi2 = 0; mi2 < 2; ++mi2){
        const unsigned short* wp = wb + (size_t)(96 + kvrow0 + mi2*16 + pos)*96 + khalf*8;
        short8 a0 = *(const short8*)(wp);
        short8 a1 = *(const short8*)(wp + 32);
        short8 a2 = *(const short8*)(wp + 64);
        float4 bv = *(const float4*)&kv_b[kvrow0 + mi2*16 + khalf*4];
        #pragma unroll
        for (int i = 0; i < 3; ++i){
          if (i >= npv) break;
          f32x4 a = {bv.x, bv.y, bv.z, bv.w};
          a = __builtin_amdgcn_mfma_f32_16x16x32_bf16(a0, xf[i][0], a, 0,0,0);
          a = __builtin_amdgcn_mfma_f32_16x16x32_bf16(a1, xf[i][1], a, 0,0,0);
          a = __builtin_amdgcn_mfma_f32_16x16x32_bf16(a2, xf[i][2], a, 0,0,0);
          #pragma unroll
          for (int r = 0; r < 4; ++r){
            int ch = mi2*16 + khalf*4 + r;
            // invalid hp lands in row pad (hx 34..39) — never read
            Ysh[ch*VYC2 + hyv[i]*VXP2 + hxv[i]] = imv[i] ? f2b(a[r]) : (unsigned short)0;
          }
        }
      }
      __syncthreads();
      // dw 3x3 — WAVE-LOCAL: wave w computes exactly row py=w (all 32 ch x both halves)
      {
        int c2 = t & 31, xh = (t >> 5) & 1, py = t >> 6;   // py == wave id
        const float* wd = kvd_w + (size_t)(kvrow0 + c2)*9;
        float w00=wd[0],w01=wd[1],w02=wd[2],w10=wd[3],w11=wd[4],w12=wd[5],w20=wd[6],w21=wd[7],w22=wd[8];
        float bb = kvd_b[kvrow0 + c2];
        float o[16];
        #pragma unroll
        for (int half = 0; half < 2; ++half){
          float u[3][10];
          #pragma unroll
          for (int uu = 0; uu < 3; ++uu){
            const unsigned short* rp = &Ysh[c2*VYC2 + (py+uu)*VXP2 + xh*16 + half*8];
            short8 s = *(const short8*)rp;
            unsigned ex = *(const unsigned*)(rp + 8);
            #pragma unroll
            for (int j = 0; j < 8; ++j) u[uu][j] = b2f((unsigned short)s[j]);
            u[uu][8] = b2f((unsigned short)(ex & 0xffffu));
            u[uu][9] = b2f((unsigned short)(ex >> 16));
          }
          #pragma unroll
          for (int j = 0; j < 8; ++j){
            float s = bb;
            s = fmaf(w00,u[0][j],s); s = fmaf(w01,u[0][j+1],s); s = fmaf(w02,u[0][j+2],s);
            s = fmaf(w10,u[1][j],s); s = fmaf(w11,u[1][j+1],s); s = fmaf(w12,u[1][j+2],s);
            s = fmaf(w20,u[2][j],s); s = fmaf(w21,u[2][j+1],s); s = fmaf(w22,u[2][j+2],s);
            o[half*8 + j] = s;
          }
        }
        int pb = py*32 + xh*16;
        #pragma unroll
        for (int jj = 0; jj < 8; ++jj){
          unsigned p = cvtpk(o[2*jj], o[2*jj+1]);
          vS[(pb + 2*jj    )*VCH + c2] = (unsigned short)p;
          vS[(pb + 2*jj + 1)*VCH + c2] = (unsigned short)(p >> 16);
        }
      }
      // NO barrier: wave w's MFMA reads only vS rows [w*32, w*32+32) which wave w wrote
      #pragma unroll
      for (int mi = 0; mi < 6; ++mi){
        short8 a = *(const short8*)(mbp + (size_t)(mi*16 + pos)*96 + ck*32 + khalf*8);
        #pragma unroll
        for (int gi = 0; gi < 2; ++gi){
          int g = 2*w + gi;
          short8 bf = *(const short8*)&vS[(size_t)(g*16 + pos)*VCH + khalf*8];
          acc[mi][gi] = __builtin_amdgcn_mfma_f32_16x16x32_bf16(a, bf, acc[mi][gi], 0,0,0);
        }
      }
      __syncthreads();
    }

    // epilogue: wave w writes row gy0+w (both 16-px halves, nt)
    float* ob = out + ((size_t)z*NB + b)*(size_t)C*NPIX;
    const int gy = gy0 + w;
    #pragma unroll
    for (int mi = 0; mi < 6; ++mi){
      #pragma unroll
      for (int r = 0; r < 4; ++r){
        float* base = &ob[(size_t)(mi*16 + khalf*4 + r)*NPIX + (size_t)gy*WW + gx0 + pos];
        __builtin_nontemporal_store(acc[mi][0][r], base);
        __builtin_nontemporal_store(acc[mi][1][r], base + 16);
      }
    }
  }
}

// ============================ fallback (r4) kernels (row-major xt) ============================
__device__ __forceinline__ void conv48c(
  const unsigned short* __restrict__ xbase, const float* __restrict__ wmat,
  const float* __restrict__ bias, int row0,
  int gx0, int gy0, int lane, int w, unsigned short* __restrict__ Ysh)
{
  const int hy = lane & 15, khalf = lane >> 4;
  const int gy = gy0 - 1 + hy;
  short8 xf[3][3]; bool imv[3]; int np = (w < 2) ? 3 : 2;
  #pragma unroll
  for (int i = 0; i < 3; ++i){
    if (i >= np) break;
    int pt = w + i*8;
    int gx = gx0 - 1 + pt;
    bool im = (gx>=0) && (gx<WW) && (gy>=0) && (gy<HH);
    imv[i] = im;
    int n = im ? (gy*WW + gx) : 0;
    const unsigned short* xp = xbase + (size_t)n*96 + khalf*8;
    short8 z = {};
    #pragma unroll
    for (int kk = 0; kk < 3; ++kk){
      short8 v = *(const short8*)(xp + kk*32);
      xf[i][kk] = im ? v : z;
    }
  }
  #pragma unroll 1
  for (int mi = 0; mi < 3; ++mi){
    int orow = row0 + mi*16 + hy;
    const float* wp = wmat + (size_t)orow*96 + khalf*8;
    short8 a0 = pack8(*(const float4*)(wp),    *(const float4*)(wp+4));
    short8 a1 = pack8(*(const float4*)(wp+32), *(const float4*)(wp+36));
    short8 a2 = pack8(*(const float4*)(wp+64), *(const float4*)(wp+68));
    float4 bv = *(const float4*)&bias[row0 + mi*16 + khalf*4];
    #pragma unroll
    for (int i = 0; i < 3; ++i){
      if (i >= np) break;
      int pt = w + i*8;
      f32x4 acc = {bv.x, bv.y, bv.z, bv.w};
      acc = __builtin_amdgcn_mfma_f32_16x16x32_bf16(a0, xf[i][0], acc, 0,0,0);
      acc = __builtin_amdgcn_mfma_f32_16x16x32_bf16(a1, xf[i][1], acc, 0,0,0);
      acc = __builtin_amdgcn_mfma_f32_16x16x32_bf16(a2, xf[i][2], acc, 0,0,0);
      #pragma unroll
      for (int r = 0; r < 4; ++r){
        int ch = mi*16 + khalf*4 + r;
        Ysh[ch*YP + pt*16 + hy] = imv[i] ? f2b(acc[r]) : (unsigned short)0;
      }
    }
  }
}

__global__ __launch_bounds__(512, 4) void kqk(
  const unsigned short* __restrict__ xt,
  const float* __restrict__ q_w, const float* __restrict__ q_b,
  const float* __restrict__ qd_w, const float* __restrict__ qd_b,
  const float* __restrict__ kv_w, const float* __restrict__ kv_b,
  const float* __restrict__ kvd_w, const float* __restrict__ kvd_b,
  float* __restrict__ pg, float* __restrict__ psq)
{
  __shared__ unsigned short Ysh[48*YP];
  __shared__ unsigned short qS[48*QP];
  __shared__ unsigned short kT[48*QP];
  __shared__ float redq[C], redk[C];

  const int t = threadIdx.x, lane = t & 63, w = t >> 6;
  const int b = blockIdx.y, tile = blockIdx.x;
  const int txx = tile & 15, tyy = tile >> 4;
  const int gx0 = txx*16, gy0 = tyy*14;
  if (t < C){ redq[t] = 0.f; redk[t] = 0.f; }
  __syncthreads();

  const unsigned short* xc = xt + ((size_t)(0*NB + b))*NPIX*96;
  const unsigned short* xs = xt + ((size_t)(1*NB + b))*NPIX*96;

  auto dwQK = [&](const float* dww, const float* dwb, int wrow0,
                  unsigned short* dst, float* red){
    for (int slot = t; slot < 48*16; slot += 512){
      int c = slot >> 4, j = slot & 15;
      const unsigned short* yb = &Ysh[c*YP + j*16];
      float u0[16], u1[16], u2[16];
      {
        short8 s0 = *(const short8*)(yb);
        short8 s1 = *(const short8*)(yb+8);
        short8 s2 = *(const short8*)(yb+16), s3 = *(const short8*)(yb+24);
        short8 s4 = *(const short8*)(yb+32), s5 = *(const short8*)(yb+40);
        #pragma unroll
        for (int u = 0; u < 8; ++u){
          u0[u]=b2f((unsigned short)s0[u]); u0[u+8]=b2f((unsigned short)s1[u]);
          u1[u]=b2f((unsigned short)s2[u]); u1[u+8]=b2f((unsigned short)s3[u]);
          u2[u]=b2f((unsigned short)s4[u]); u2[u+8]=b2f((unsigned short)s5[u]);
        }
      }
      const float* wd = dww + (size_t)(wrow0 + c)*9;
      float w00=wd[0],w01=wd[1],w02=wd[2],w10=wd[3],w11=wd[4],w12=wd[5],w20=wd[6],w21=wd[7],w22=wd[8];
      float bb = dwb[wrow0 + c];
      unsigned short vv[16];
      float sq = 0.f;
      #pragma unroll
      for (int py = 0; py < 14; ++py){
        float s = bb;
        s = fmaf(w00,u0[py],s); s = fmaf(w10,u0[py+1],s); s = fmaf(w20,u0[py+2],s);
        s = fmaf(w01,u1[py],s); s = fmaf(w11,u1[py+1],s); s = fmaf(w21,u1[py+2],s);
        s = fmaf(w02,u2[py],s); s = fmaf(w12,u2[py+1],s); s = fmaf(w22,u2[py+2],s);
        if (gy0 + py >= HH) s = 0.f;
        sq = fmaf(s, s, sq);
        vv[py] = f2b(s);
      }
      vv[14] = 0; vv[15] = 0;
      atomicAdd(&red[wrow0 + c], sq);
      *(short8*)&dst[c*QP + j*16]     = *(short8*)&vv[0];
      *(short8*)&dst[c*QP + j*16 + 8] = *(short8*)&vv[8];
    }
  };

  auto gram = [&](int cc){
    int hl = w & 1, slice = w >> 1;
    int cl = lane & 31; bool cv = cl < CH;
    int row = hl*CH + (cv ? cl : 0);
    f32x16 g;
    #pragma unroll
    for (int r = 0; r < 16; ++r) g[r] = 0.f;
    short8 z = {};
    for (int ks = slice; ks < 16; ks += 4){
      int ko = ks*16 + (lane>>5)*8;
      short8 qa = *(const short8*)&qS[row*QP + ko];
      short8 kb = *(const short8*)&kT[row*QP + ko];
      if (!cv){ qa = z; kb = z; }
      g = __builtin_amdgcn_mfma_f32_32x32x16_bf16(qa, kb, g, 0,0,0);
    }
    float* stg = (float*)Ysh;
    if (slice != 0){
      float* dst = stg + (size_t)(hl*3 + slice - 1)*1024;
      #pragma unroll
      for (int r = 0; r < 16; ++r) dst[r*64 + lane] = g[r];
    }
    __syncthreads();
    if (slice == 0){
      const float* s0 = stg + (size_t)(hl*3 + 0)*1024;
      const float* s1 = stg + (size_t)(hl*3 + 1)*1024;
      const float* s2 = stg + (size_t)(hl*3 + 2)*1024;
      float* dst = pg + ((size_t)(tile*NB + b)*HEADS + cc*2 + hl)*1024;
      #pragma unroll
      for (int r = 0; r < 16; ++r){
        int ix = r*64 + lane;
        dst[ix] = g[r] + s0[ix] + s1[ix] + s2[ix];
      }
    }
  };

  #pragma unroll 1
  for (int cc = 0; cc < 2; ++cc){
    conv48c(xc, q_w, q_b, cc*48, gx0, gy0, lane, w, Ysh);
    __syncthreads();
    dwQK(qd_w, qd_b, cc*48, qS, redq);
    __syncthreads();
    conv48c(xs, kv_w, kv_b, cc*48, gx0, gy0, lane, w, Ysh);
    __syncthreads();
    dwQK(kvd_w, kvd_b, cc*48, kT, redk);
    __syncthreads();
    gram(cc);
    __syncthreads();
  }
  if (t < 192){
    float v = (t < 96) ? redq[t] : redk[t - 96];
    psq[(size_t)(tile*NB + b)*192 + t] = v;
  }
}

__global__ __launch_bounds__(256) void kgredF(
  const float* __restrict__ pg, const float* __restrict__ psq, float* __restrict__ ws)
{
  const int bh = blockIdx.x;
  const int b = bh >> 2, h = bh & 3;
  const int t = threadIdx.x;
  float a0=0.f, a1=0.f, a2=0.f, a3=0.f, sq=0.f;
  for (int tile = 0; tile < NTILES; ++tile){
    const float* p = pg + ((size_t)(tile*NB + b)*HEADS + h)*1024;
    a0 += p[t]; a1 += p[t+256]; a2 += p[t+512]; a3 += p[t+768];
    if (t < 48){
      int ch = h*CH + (t % CH);
      sq += psq[(size_t)(tile*NB + b)*192 + (t < CH ? ch : 96 + ch)];
    }
  }
  if (t < 48){
    if (t < CH) ws[WS_SUMSQ_Q + b*C + h*CH + t] = sq;
    else        ws[WS_SUMSQ_K + b*C + h*CH + (t - CH)] = sq;
  }
  float accs[4] = {a0, a1, a2, a3};
  #pragma unroll
  for (int i = 0; i < 4; ++i){
    int idx = i*256 + t;
    int r = idx >> 6, ln = idx & 63;
    int row = (r&3) + 8*(r>>2) + 4*(ln>>5);
    int col = ln & 31;
    if (row < CH && col < CH)
      ws[WS_GRAM + ((size_t)(b*HEADS + h)*CH + row)*CH + col] = accs[i];
  }
}

__global__ __launch_bounds__(512, 4) void kv_out(
  const unsigned short* __restrict__ xs,
  const float* __restrict__ kv_w, const float* __restrict__ kv_b,
  const float* __restrict__ kvd_w, const float* __restrict__ kvd_b,
  const float* __restrict__ ps_b, const float* __restrict__ psh_b,
  const unsigned short* __restrict__ mb, float* __restrict__ out)
{
  __shared__ unsigned short Ysh[48*YP];
  __shared__ unsigned short vS2[224*VP];
  const int t = threadIdx.x, lane = t & 63, w = t >> 6;
  const int b = blockIdx.y, tile = blockIdx.x;
  const int txx = tile & 15, tyy = tile >> 4;
  const int gx0 = txx*16, gy0 = tyy*14;
  const unsigned short* xb_ = xs + (size_t)b*NPIX*96;

  #pragma unroll 1
  for (int which = 0; which < 2; ++which){
    #pragma unroll 1
    for (int cv = 0; cv < 2; ++cv){
      int row0 = 96 + which*96 + cv*48;
      conv48c(xb_, kv_w, kv_b, row0, gx0, gy0, lane, w, Ysh);
      __syncthreads();
      for (int slot = t; slot < 48*16; slot += 512){
        int c = slot >> 4, j = slot & 15;
        const unsigned short* yb = &Ysh[c*YP + j*16];
        float u0[16], u1[16], u2[16];
        {
          short8 s0 = *(const short8*)(yb),    s1 = *(const short8*)(yb+8);
          short8 s2 = *(const short8*)(yb+16), s3 = *(const short8*)(yb+24);
          short8 s4 = *(const short8*)(yb+32), s5 = *(const short8*)(yb+40);
          #pragma unroll
          for (int u = 0; u < 8; ++u){
            u0[u]=b2f((unsigned short)s0[u]); u0[u+8]=b2f((unsigned short)s1[u]);
            u1[u]=b2f((unsigned short)s2[u]); u1[u+8]=b2f((unsigned short)s3[u]);
            u2[u]=b2f((unsigned short)s4[u]); u2[u+8]=b2f((unsigned short)s5[u]);
          }
        }
        const float* wd = kvd_w + (size_t)(row0 + c)*9;
        float w00=wd[0],w01=wd[1],w02=wd[2],w10=wd[3],w11=wd[4],w12=wd[5],w20=wd[6],w21=wd[7],w22=wd[8];
        float bb = kvd_b[row0 + c];
        #pragma unroll
        for (int py = 0; py < 14; ++py){
          float s = bb;
          s = fmaf(w00,u0[py],s); s = fmaf(w10,u0[py+1],s); s = fmaf(w20,u0[py+2],s);
          s = fmaf(w01,u1[py],s); s = fmaf(w11,u1[py+1],s); s = fmaf(w21,u1[py+2],s);
          s = fmaf(w02,u2[py],s); s = fmaf(w12,u2[py+1],s); s = fmaf(w22,u2[py+2],s);
          vS2[(py*16 + j)*VP + cv*48 + c] = f2b(s);
        }
      }
      __syncthreads();
    }
    const unsigned short* mbp = mb + ((size_t)which*NB + b)*9216;
    const float* bias = which ? psh_b : ps_b;
    float* ob = out + (size_t)which*NB*C*NPIX + (size_t)b*C*NPIX;
    for (int tl = w; tl < 84; tl += 8){
      int mi = tl / 14, n = tl - mi*14;
      const unsigned short* mp = mbp + (size_t)(mi*16 + (lane&15))*96 + (lane>>4)*8;
      short8 a0 = *(const short8*)(mp);
      short8 a1 = *(const short8*)(mp + 32);
      short8 a2 = *(const short8*)(mp + 64);
      float4 bv = *(const float4*)&bias[mi*16 + (lane>>4)*4];
      f32x4 acc = {bv.x, bv.y, bv.z, bv.w};
      const unsigned short* xb = &vS2[(size_t)(n*16 + (lane&15))*VP + (lane>>4)*8];
      acc = __builtin_amdgcn_mfma_f32_16x16x32_bf16(a0, *(const short8*)(xb),    acc, 0,0,0);
      acc = __builtin_amdgcn_mfma_f32_16x16x32_bf16(a1, *(const short8*)(xb+32), acc, 0,0,0);
      acc = __builtin_amdgcn_mfma_f32_16x16x32_bf16(a2, *(const short8*)(xb+64), acc, 0,0,0);
      int gy = gy0 + n;
      if (gy < HH){
        #pragma unroll
        for (int r = 0; r < 4; ++r)
          ob[(size_t)(mi*16 + (lane>>4)*4 + r)*NPIX + gy*WW + gx0 + (lane&15)] = acc[r];
      }
    }
    __syncthreads();
  }
}

extern "C" void kernel_launch(void* const* d_in, const int* in_sizes, int n_in,
                              void* d_out, int out_size, void* d_ws, size_t ws_size,
                              hipStream_t stream)
{
  const float* content = (const float*)d_in[0];
  const float* style   = (const float*)d_in[1];
  const float* temp    = (const float*)d_in[2];
  const float* q_w   = (const float*)d_in[3];
  const float* q_b   = (const float*)d_in[4];
  const float* qd_w  = (const float*)d_in[5];
  const float* qd_b  = (const float*)d_in[6];
  const float* kv_w  = (const float*)d_in[7];
  const float* kv_b  = (const float*)d_in[8];
  const float* kvd_w = (const float*)d_in[9];
  const float* kvd_b = (const float*)d_in[10];
  const float* ps_w  = (const float*)d_in[11];
  const float* ps_b  = (const float*)d_in[12];
  const float* psh_w = (const float*)d_in[13];
  const float* psh_b = (const float*)d_in[14];
  float* out = (float*)d_out;
  float* ws  = (float*)d_ws;

  unsigned short* xt = (unsigned short*)((char*)d_ws + XT_OFF_BYTES);

  if (ws_size >= WS_NEED3){
    unsigned short* qk  = (unsigned short*)((char*)d_ws + QK_OFF);
    float* pg  = (float*)((char*)d_ws + PG_OFF);
    float* psq = (float*)((char*)d_ws + PSQ_OFF);
    unsigned short* mb = (unsigned short*)((char*)d_ws + MB_OFF);
    unsigned short* wb = (unsigned short*)((char*)d_ws + WB_OFF);

    k0t<<<dim3(NPIX/64, NB, 2), dim3(256), 0, stream>>>(content, style, xt, 1);
    kwpack<<<dim3(144), dim3(256), 0, stream>>>(q_w, kv_w, wb);
    kconv<<<dim3(NTILES, NB, 4), dim3(512), 0, stream>>>(
        xt, wb, q_b, qd_w, qd_b, kv_b, kvd_w, kvd_b, qk, psq);
    kgram<<<dim3(KSPLIT, NB), dim3(384), 0, stream>>>(qk, pg);
    kgredN<<<dim3(NB, 37), dim3(256), 0, stream>>>(pg, psq, ws);
    k2_attn<<<dim3(NB), dim3(256), 0, stream>>>(temp, ps_w, psh_w, ws, mb);
    kvm<<<dim3(NTV2, NB), dim3(512), 0, stream>>>(
        xt, wb, kv_b, kvd_w, kvd_b, mb, ps_b, psh_b, out);
  } else {
    float* pg  = (float*)((char*)d_ws + F_PG_OFF);
    float* psq = (float*)((char*)d_ws + F_PSQ_OFF);
    unsigned short* mb = (unsigned short*)((char*)d_ws + F_MB_OFF);
    k0t<<<dim3(NPIX/64, NB, 2), dim3(256), 0, stream>>>(content, style, xt, 0);
    kqk<<<dim3(NTILES, NB), dim3(512), 0, stream>>>(
        xt, q_w, q_b, qd_w, qd_b, kv_w, kv_b, kvd_w, kvd_b, pg, psq);
    kgredF<<<dim3(NB*HEADS), dim3(256), 0, stream>>>(pg, psq, ws);
    k2_attn<<<dim3(NB), dim3(256), 0, stream>>>(temp, ps_w, psh_w, ws, mb);
    kv_out<<<dim3(NTILES, NB), dim3(512), 0, stream>>>(
        xt + (size_t)NB*NPIX*96, kv_w, kv_b, kvd_w, kvd_b, ps_b, psh_b, mb, out);
  }
}

// Round 18
// 388.315 us; speedup vs baseline: 1.0655x; 1.0655x over previous
//
#include <hip/hip_runtime.h>

#define NB 4
#define C 96
#define HH 256
#define WW 256
#define NPIX (HH*WW)
#define HEADS 4
#define CH 24

// ---- kconv tiling: interior 16 wide x 14 tall, halo 18x16 ----
#define NTX2 16
#define NTY2 19
#define NTILES (NTX2*NTY2)
#define YP 296      // fallback Ysh pitch
#define QP 264      // fallback qS/kT pitch
#define VP 104      // fallback vS pitch
#define KSPLIT 128
#define YR 24       // kconv Ysh row pitch (shorts)
#define YC 392      // kconv Ysh channel stride (shorts)
#define XTP 76      // k0t LDS pitch (shorts)
#define VCH 40      // kvm vS pitch (shorts)

// ---- kvm tiling: interior 32 wide x 8 tall (exact), halo 34x10 ----
#define VHP2 340    // halo pixels
#define VXP2 40     // Ysh row pitch (shorts)
#define VYC2 400    // Ysh channel stride (10*40)
#define NTV2 256    // 8 x 32 tiles

#define WS_SUMSQ_Q 0
#define WS_SUMSQ_K (WS_SUMSQ_Q + NB*C)
#define WS_GRAM    (WS_SUMSQ_K + NB*C)
#define WS_MS      (WS_GRAM + NB*HEADS*CH*CH)
#define WS_MSH     (WS_MS + NB*C*C)

// shared xt region
#define XT_OFF_BYTES ((size_t)335872)
#define XT_BYTES   ((size_t)2*NB*NPIX*96*2)

// ---- fallback (r4) layout ----
#define F_PSQ_OFF   (XT_OFF_BYTES + XT_BYTES)
#define F_PSQ_BYTES ((size_t)NTILES*NB*192*4)
#define F_PG_OFF    (F_PSQ_OFF + F_PSQ_BYTES)
#define F_PG_BYTES  ((size_t)NTILES*NB*HEADS*1024*4)
#define F_MB_OFF    (F_PG_OFF + F_PG_BYTES)
#define F_MB_BYTES  ((size_t)2*NB*96*96*2)
#define F_WS_NEED   (F_MB_OFF + F_MB_BYTES)

// ---- main layout ----
#define QK_OFF    (XT_OFF_BYTES + XT_BYTES)
#define QK_BYTES  ((size_t)2*NB*96*NPIX*2)
#define PG_OFF    (QK_OFF + QK_BYTES)
#define PG_BYTES  ((size_t)KSPLIT*NB*9216*4)
#define PSQ_OFF   (PG_OFF + PG_BYTES)
#define PSQ_BYTES ((size_t)4*NTILES*NB*48*4)
#define MB_OFF    (PSQ_OFF + PSQ_BYTES)
#define MB_BYTES  ((size_t)2*NB*96*96*2)
#define WB_OFF    (MB_OFF + MB_BYTES)
#define WB_BYTES  ((size_t)384*96*2)
#define WS_NEED3  (WB_OFF + WB_BYTES)

typedef short short8 __attribute__((ext_vector_type(8)));
typedef float f32x4 __attribute__((ext_vector_type(4)));
typedef float f32x16 __attribute__((ext_vector_type(16)));

__device__ __forceinline__ unsigned short f2b(float f){
  unsigned u = __float_as_uint(f);
  unsigned r = u + 0x7FFFu + ((u >> 16) & 1u);
  return (unsigned short)(r >> 16);
}
__device__ __forceinline__ float b2f(unsigned short s){
  return __uint_as_float(((unsigned)s) << 16);
}
__device__ __forceinline__ unsigned cvtpk(float lo, float hi){
  unsigned r;
  asm("v_cvt_pk_bf16_f32 %0, %1, %2" : "=v"(r) : "v"(lo), "v"(hi));
  return r;
}
__device__ __forceinline__ short8 pack8(float4 a, float4 b){
  short8 r;
  r[0]=(short)f2b(a.x); r[1]=(short)f2b(a.y); r[2]=(short)f2b(a.z); r[3]=(short)f2b(a.w);
  r[4]=(short)f2b(b.x); r[5]=(short)f2b(b.y); r[6]=(short)f2b(b.z); r[7]=(short)f2b(b.w);
  return r;
}

// ============================ K0: fp32 [c][gy][gx] -> bf16 [px][c]; cm=1: px = gx*HH+gy ============================
__global__ __launch_bounds__(256) void k0t(
  const float* __restrict__ content, const float* __restrict__ style,
  unsigned short* __restrict__ xt, int cm)
{
  __shared__ unsigned short Xt[96*XTP];
  const int t = threadIdx.x;
  const int n0 = blockIdx.x * 64;
  const int b = blockIdx.y, src = blockIdx.z;
  const int gyr = n0 >> 8, gxb = n0 & 255;
  const float* in = (src ? style : content) + (size_t)b*C*NPIX;
  #pragma unroll
  for (int i = 0; i < 6; ++i){
    int s = i*256 + t;
    int r = s >> 4, c4 = s & 15;
    float4 f = *(const float4*)(in + (size_t)r*NPIX + n0 + c4*4);
    unsigned lo = ((unsigned)f2b(f.y) << 16) | f2b(f.x);
    unsigned hi = ((unsigned)f2b(f.w) << 16) | f2b(f.z);
    *(uint2*)&Xt[r*XTP + c4*4] = make_uint2(lo, hi);
  }
  __syncthreads();
  unsigned* dst = (unsigned*)(xt + ((size_t)src*NB + b)*NPIX*96);
  #pragma unroll
  for (int i = 0; i < 12; ++i){
    int s = i*256 + t;
    int j = s / 48, c2 = s - j*48;
    unsigned v = ((unsigned)Xt[(c2*2+1)*XTP + j] << 16) | Xt[(c2*2)*XTP + j];
    size_t np = cm ? ((size_t)(gxb + j)*HH + gyr) : (size_t)(n0 + j);
    dst[np*48 + c2] = v;
  }
}

// ============================ kwpack ============================
__global__ __launch_bounds__(256) void kwpack(
  const float* __restrict__ q_w, const float* __restrict__ kv_w,
  unsigned short* __restrict__ wb)
{
  int i = blockIdx.x*256 + threadIdx.x;
  if (i < 9216) wb[i] = f2b(q_w[i]);
  else if (i < 36864) wb[i] = f2b(kv_w[i - 9216]);
}

// ============================ kconv: q,k only. z: 0,1 q (content); 2,3 k (style) ============================
__global__ __launch_bounds__(512, 4) void kconv(
  const unsigned short* __restrict__ xt, const unsigned short* __restrict__ wb,
  const float* __restrict__ q_b, const float* __restrict__ qd_w, const float* __restrict__ qd_b,
  const float* __restrict__ kv_b, const float* __restrict__ kvd_w, const float* __restrict__ kvd_b,
  unsigned short* __restrict__ qk, float* __restrict__ psq)
{
  __shared__ unsigned short Ysh[48*YC];   // 37632 B
  __shared__ float red[48];
  const int t = threadIdx.x, lane = t & 63, w = t >> 6;
  const int tile = blockIdx.x, b = blockIdx.y, z = blockIdx.z;
  const int txx = tile & 15, tyy = tile >> 4;
  const int gx0 = txx*16, gy0 = tyy*14;
  const unsigned short* xsrc = xt + ((size_t)((z < 2 ? 0 : 1)*NB + b))*NPIX*96;
  const int wrow0 = (z < 2) ? z*48 : 96 + (z-2)*48;
  const float* cb  = (z<2) ? q_b  + z*48           : kv_b  + (size_t)(z-2)*48;
  const float* dww = (z<2) ? qd_w + (size_t)z*48*9 : kvd_w + (size_t)(z-2)*48*9;
  const float* dwb = (z<2) ? qd_b + z*48           : kvd_b + (size_t)(z-2)*48;
  unsigned short* dst0 = (z < 2)
      ? qk + ((size_t)(0*NB + b)*96 + (size_t)z*48)*NPIX
      : qk + ((size_t)(1*NB + b)*96 + (size_t)(z-2)*48)*NPIX;

  if (t < 48) red[t] = 0.f;

  // persistent halo fragments — xt column-major
  const int hy = lane & 15, khalf = lane >> 4;
  const int gyh = gy0 - 1 + hy;
  short8 xf[3][3]; bool imv[3];
  const int np = (w < 2) ? 3 : 2;
  #pragma unroll
  for (int i = 0; i < 3; ++i){
    if (i >= np) break;
    int pt = w + i*8;
    int gx = gx0 - 1 + pt;
    bool im = (gx>=0) && (gx<WW) && (gyh>=0) && (gyh<HH);
    imv[i] = im;
    const unsigned short* xp = xsrc + (size_t)(im ? (gx*HH + gyh) : 0)*96 + khalf*8;
    short8 zz = {};
    #pragma unroll
    for (int kk = 0; kk < 3; ++kk){
      short8 v = *(const short8*)(xp + kk*32);
      xf[i][kk] = im ? v : zz;
    }
  }

  // conv1x1: 48 output rows over halo -> Ysh [ch][hy][pt]
  #pragma unroll 1
  for (int mi = 0; mi < 3; ++mi){
    const unsigned short* wp = wb + (size_t)(wrow0 + mi*16 + hy)*96 + khalf*8;
    short8 a0 = *(const short8*)(wp);
    short8 a1 = *(const short8*)(wp + 32);
    short8 a2 = *(const short8*)(wp + 64);
    float4 bv = *(const float4*)&cb[mi*16 + khalf*4];
    #pragma unroll
    for (int i = 0; i < 3; ++i){
      if (i >= np) break;
      int pt = w + i*8;
      f32x4 acc = {bv.x, bv.y, bv.z, bv.w};
      acc = __builtin_amdgcn_mfma_f32_16x16x32_bf16(a0, xf[i][0], acc, 0,0,0);
      acc = __builtin_amdgcn_mfma_f32_16x16x32_bf16(a1, xf[i][1], acc, 0,0,0);
      acc = __builtin_amdgcn_mfma_f32_16x16x32_bf16(a2, xf[i][2], acc, 0,0,0);
      #pragma unroll
      for (int r = 0; r < 4; ++r){
        int ch = mi*16 + khalf*4 + r;
        Ysh[ch*YC + hy*YR + pt] = imv[i] ? f2b(acc[r]) : (unsigned short)0;
      }
    }
  }
  __syncthreads();

  // dw 3x3, wave-balanced
  for (int sl = lane; sl < 84; sl += 64){
    int slot = w*84 + sl;                 // 0..671
    int c = slot / 14, py = slot - (slot/14)*14;
    int gy = gy0 + py;
    if (gy < HH){
      const float* wd = dww + (size_t)c*9;
      float w00=wd[0],w01=wd[1],w02=wd[2],w10=wd[3],w11=wd[4],w12=wd[5],w20=wd[6],w21=wd[7],w22=wd[8];
      float bb = dwb[c];
      const unsigned short* yb = &Ysh[c*YC + py*YR];
      float o[16];
      #pragma unroll
      for (int half = 0; half < 2; ++half){
        float u[3][10];
        #pragma unroll
        for (int uu = 0; uu < 3; ++uu){
          const unsigned short* rp = yb + uu*YR + half*8;
          short8 s = *(const short8*)rp;
          unsigned ex = *(const unsigned*)(rp + 8);
          #pragma unroll
          for (int j = 0; j < 8; ++j) u[uu][j] = b2f((unsigned short)s[j]);
          u[uu][8] = b2f((unsigned short)(ex & 0xffffu));
          u[uu][9] = b2f((unsigned short)(ex >> 16));
        }
        #pragma unroll
        for (int j = 0; j < 8; ++j){
          float s = bb;
          s = fmaf(w00,u[0][j],s); s = fmaf(w01,u[0][j+1],s); s = fmaf(w02,u[0][j+2],s);
          s = fmaf(w10,u[1][j],s); s = fmaf(w11,u[1][j+1],s); s = fmaf(w12,u[1][j+2],s);
          s = fmaf(w20,u[2][j],s); s = fmaf(w21,u[2][j+1],s); s = fmaf(w22,u[2][j+2],s);
          o[half*8 + j] = s;
        }
      }
      float sq = 0.f;
      #pragma unroll
      for (int j = 0; j < 16; ++j) sq = fmaf(o[j], o[j], sq);
      atomicAdd(&red[c], sq);
      unsigned vvp[8];
      #pragma unroll
      for (int jj = 0; jj < 8; ++jj) vvp[jj] = cvtpk(o[2*jj], o[2*jj+1]);
      unsigned short* qp = dst0 + (size_t)c*NPIX + (size_t)gy*WW + gx0;
      *(uint4*)qp       = make_uint4(vvp[0], vvp[1], vvp[2], vvp[3]);
      *(uint4*)(qp + 8) = make_uint4(vvp[4], vvp[5], vvp[6], vvp[7]);
    }
  }
  __syncthreads();
  if (t < 48)
    psq[((size_t)(z*NTILES + tile)*NB + b)*48 + t] = red[t];
}

// ============================ kgram: partial-K Gram ============================
__global__ __launch_bounds__(384) void kgram(
  const unsigned short* __restrict__ qk, float* __restrict__ pg)
{
  const int t = threadIdx.x, lane = t & 63, wv = t >> 6;
  const int ks = blockIdx.x, b = blockIdx.y;
  const int n0 = ks * (NPIX / KSPLIT);
  const unsigned short* qb = qk + ((size_t)(0*NB + b)*96)*NPIX;
  const unsigned short* kb = qk + ((size_t)(1*NB + b)*96)*NPIX;
  f32x4 acc[6];
  #pragma unroll
  for (int i = 0; i < 6; ++i) acc[i] = (f32x4){0.f,0.f,0.f,0.f};
  #pragma unroll 1
  for (int st = 0; st < (NPIX/KSPLIT)/32; ++st){
    int off = n0 + st*32 + (lane>>4)*8;
    short8 bf = *(const short8*)(kb + (size_t)(wv*16 + (lane&15))*NPIX + off);
    #pragma unroll
    for (int ci = 0; ci < 6; ++ci){
      short8 af = *(const short8*)(qb + (size_t)(ci*16 + (lane&15))*NPIX + off);
      acc[ci] = __builtin_amdgcn_mfma_f32_16x16x32_bf16(af, bf, acc[ci], 0,0,0);
    }
  }
  float* dst = pg + ((size_t)ks*NB + b)*9216;
  #pragma unroll
  for (int ci = 0; ci < 6; ++ci){
    #pragma unroll
    for (int r = 0; r < 4; ++r)
      dst[(ci*6 + wv)*256 + ((lane>>4)*4 + r)*16 + (lane&15)] = acc[ci][r];
  }
}

// ============================ kgredN ============================
__global__ __launch_bounds__(256) void kgredN(
  const float* __restrict__ pg, const float* __restrict__ psq, float* __restrict__ ws)
{
  const int b = blockIdx.x, by = blockIdx.y, t = threadIdx.x;
  if (by < 36){
    int ci = by / 6;
    int qrow = ci*16 + (t >> 4), krow = (by - ci*6)*16 + (t & 15);
    float s = 0.f;
    for (int ks = 0; ks < KSPLIT; ++ks)
      s += pg[((size_t)ks*NB + b)*9216 + by*256 + t];
    int h = qrow / CH;
    if (krow / CH == h)
      ws[WS_GRAM + ((size_t)(b*HEADS + h)*CH + (qrow % CH))*CH + (krow % CH)] = s;
  } else {
    if (t < 192){
      int src = t / 96, c = t - (t/96)*96;
      int zz = src*2 + (c/48), cc = c - (c/48)*48;
      float s = 0.f;
      for (int tile = 0; tile < NTILES; ++tile)
        s += psq[((size_t)(zz*NTILES + tile)*NB + b)*48 + cc];
      ws[(src ? WS_SUMSQ_K : WS_SUMSQ_Q) + b*C + c] = s;
    }
  }
}

// ============================ k2: softmax + M matrices ============================
__global__ void k2_attn(
  const float* __restrict__ temp,
  const float* __restrict__ ps_w, const float* __restrict__ psh_w,
  float* __restrict__ ws, unsigned short* __restrict__ mb)
{
  const int b = blockIdx.x;
  const int t = threadIdx.x;
  __shared__ float attn[C * CH];
  __shared__ float nq[C], nk[C];
  if (t < C){
    nq[t] = fmaxf(sqrtf(ws[WS_SUMSQ_Q + b * C + t]), 1e-12f);
    nk[t] = fmaxf(sqrtf(ws[WS_SUMSQ_K + b * C + t]), 1e-12f);
  }
  __syncthreads();
  if (t < C){
    int h = t / CH;
    const float* g = ws + WS_GRAM + (((size_t)b * HEADS + h) * CH + (t % CH)) * CH;
    float tp = temp[h];
    float row[CH];
    float mx = -3.4e38f;
    #pragma unroll
    for (int d = 0; d < CH; ++d){
      row[d] = g[d] / (nq[t] * nk[h * CH + d]) * tp;
      mx = fmaxf(mx, row[d]);
    }
    float s = 0.f;
    #pragma unroll
    for (int d = 0; d < CH; ++d){ row[d] = expf(row[d] - mx); s += row[d]; }
    float inv = 1.f / s;
    #pragma unroll
    for (int d = 0; d < CH; ++d) attn[t * CH + d] = row[d] * inv;
  }
  __syncthreads();
  for (int idx = t; idx < C * C; idx += 256){
    int o = idx / C, dg = idx - o * C;
    int h = dg / CH, d = dg - h * CH;
    float s1 = 0.f, s2 = 0.f;
    #pragma unroll
    for (int c2 = 0; c2 < CH; ++c2){
      float a = attn[(h * CH + c2) * CH + d];
      s1 = fmaf(ps_w [(size_t)o * C + h * CH + c2], a, s1);
      s2 = fmaf(psh_w[(size_t)o * C + h * CH + c2], a, s2);
    }
    ws[WS_MS  + (size_t)b * C * C + idx] = s1;
    ws[WS_MSH + (size_t)b * C * C + idx] = s2;
    if (mb){
      mb[((size_t)0*NB + b)*9216 + idx] = f2b(s1);
      mb[((size_t)1*NB + b)*9216 + idx] = f2b(s2);
    }
  }
}

// ============================ kvm: fused v conv+dw+M-transform, 32x8 tiles, wave-local dw->PV ============================
// z: 0 = scale, 1 = shift. 3 chunks of 32 v-channels, K=32 MFMA accumulate in regs.
__global__ __launch_bounds__(512, 4) void kvm(
  const unsigned short* __restrict__ xt, const unsigned short* __restrict__ wb,
  const float* __restrict__ kv_b, const float* __restrict__ kvd_w, const float* __restrict__ kvd_b,
  const unsigned short* __restrict__ mb,
  const float* __restrict__ ps_b, const float* __restrict__ psh_b,
  float* __restrict__ out)
{
  __shared__ unsigned short Ysh[32*VYC2];   // 25600 B
  __shared__ unsigned short vS[256*VCH];    // 20480 B
  const int t = threadIdx.x, lane = t & 63, w = t >> 6;
  const int tile = blockIdx.x, b = blockIdx.y, z = blockIdx.z;
  const int gx0 = (tile & 7)*32, gy0 = (tile >> 3)*8;
  const unsigned short* xsrc = xt + ((size_t)(NB + b))*NPIX*96;   // style

  // halo fragments: hp linearized down 10-px columns (matches column-major xt)
  const int pos = lane & 15, khalf = lane >> 4;
  const int npv = (w < 6) ? 3 : 2;     // 22 groups of 16 halo px over 8 waves
  short8 xf[3][3]; bool imv[3]; int hxv[3], hyv[3];
  #pragma unroll
  for (int i = 0; i < 3; ++i){
    if (i >= npv) break;
    int hp = (w + i*8)*16 + pos;       // 0..351 (valid < 340)
    int hx = hp / 10, hyy = hp - hx*10;
    hxv[i] = hx; hyv[i] = hyy;
    int gx = gx0 - 1 + hx, gy = gy0 - 1 + hyy;
    bool im = (hp < VHP2) && (gx>=0) && (gx<WW) && (gy>=0) && (gy<HH);
    imv[i] = im;
    const unsigned short* xp = xsrc + (size_t)(im ? (gx*HH + gy) : 0)*96 + khalf*8;
    short8 zz = {};
    #pragma unroll
    for (int kk = 0; kk < 3; ++kk){
      short8 v = *(const short8*)(xp + kk*32);
      xf[i][kk] = im ? v : zz;
    }
  }

  const float* bias = z ? psh_b : ps_b;
  f32x4 acc[6][2];
  #pragma unroll
  for (int mi = 0; mi < 6; ++mi){
    float4 bv = *(const float4*)&bias[mi*16 + khalf*4];
    acc[mi][0] = (f32x4){bv.x, bv.y, bv.z, bv.w};
    acc[mi][1] = acc[mi][0];
  }
  const unsigned short* mbp = mb + ((size_t)z*NB + b)*9216;

  #pragma unroll 1
  for (int ck = 0; ck < 3; ++ck){
    const int kvrow0 = 96 + z*96 + ck*32;   // row within kv (96..287)
    // conv1x1: 32 rows over halo -> Ysh [ch][hyy][hx]
    #pragma unroll 1
    for (int mi2 = 0; mi2 < 2; ++mi2){
      const unsigned short* wp = wb + (size_t)(96 + kvrow0 + mi2*16 + pos)*96 + khalf*8;
      short8 a0 = *(const short8*)(wp);
      short8 a1 = *(const short8*)(wp + 32);
      short8 a2 = *(const short8*)(wp + 64);
      float4 bv = *(const float4*)&kv_b[kvrow0 + mi2*16 + khalf*4];
      #pragma unroll
      for (int i = 0; i < 3; ++i){
        if (i >= npv) break;
        f32x4 a = {bv.x, bv.y, bv.z, bv.w};
        a = __builtin_amdgcn_mfma_f32_16x16x32_bf16(a0, xf[i][0], a, 0,0,0);
        a = __builtin_amdgcn_mfma_f32_16x16x32_bf16(a1, xf[i][1], a, 0,0,0);
        a = __builtin_amdgcn_mfma_f32_16x16x32_bf16(a2, xf[i][2], a, 0,0,0);
        #pragma unroll
        for (int r = 0; r < 4; ++r){
          int ch = mi2*16 + khalf*4 + r;
          // invalid hp lands in row pad (hx 34..39) — never read
          Ysh[ch*VYC2 + hyv[i]*VXP2 + hxv[i]] = imv[i] ? f2b(a[r]) : (unsigned short)0;
        }
      }
    }
    __syncthreads();
    // dw 3x3 — WAVE-LOCAL: wave w computes exactly row py=w (all 32 ch x both halves)
    {
      int c2 = t & 31, xh = (t >> 5) & 1, py = t >> 6;   // py == wave id
      const float* wd = kvd_w + (size_t)(kvrow0 + c2)*9;
      float w00=wd[0],w01=wd[1],w02=wd[2],w10=wd[3],w11=wd[4],w12=wd[5],w20=wd[6],w21=wd[7],w22=wd[8];
      float bb = kvd_b[kvrow0 + c2];
      float o[16];
      #pragma unroll
      for (int half = 0; half < 2; ++half){
        float u[3][10];
        #pragma unroll
        for (int uu = 0; uu < 3; ++uu){
          const unsigned short* rp = &Ysh[c2*VYC2 + (py+uu)*VXP2 + xh*16 + half*8];
          short8 s = *(const short8*)rp;
          unsigned ex = *(const unsigned*)(rp + 8);
          #pragma unroll
          for (int j = 0; j < 8; ++j) u[uu][j] = b2f((unsigned short)s[j]);
          u[uu][8] = b2f((unsigned short)(ex & 0xffffu));
          u[uu][9] = b2f((unsigned short)(ex >> 16));
        }
        #pragma unroll
        for (int j = 0; j < 8; ++j){
          float s = bb;
          s = fmaf(w00,u[0][j],s); s = fmaf(w01,u[0][j+1],s); s = fmaf(w02,u[0][j+2],s);
          s = fmaf(w10,u[1][j],s); s = fmaf(w11,u[1][j+1],s); s = fmaf(w12,u[1][j+2],s);
          s = fmaf(w20,u[2][j],s); s = fmaf(w21,u[2][j+1],s); s = fmaf(w22,u[2][j+2],s);
          o[half*8 + j] = s;
        }
      }
      int pb = py*32 + xh*16;
      #pragma unroll
      for (int jj = 0; jj < 8; ++jj){
        unsigned p = cvtpk(o[2*jj], o[2*jj+1]);
        vS[(pb + 2*jj    )*VCH + c2] = (unsigned short)p;
        vS[(pb + 2*jj + 1)*VCH + c2] = (unsigned short)(p >> 16);
      }
    }
    // NO barrier: wave w's MFMA reads only vS rows [w*32, w*32+32) which wave w wrote
    #pragma unroll
    for (int mi = 0; mi < 6; ++mi){
      short8 a = *(const short8*)(mbp + (size_t)(mi*16 + pos)*96 + ck*32 + khalf*8);
      #pragma unroll
      for (int gi = 0; gi < 2; ++gi){
        int g = 2*w + gi;
        short8 bf = *(const short8*)&vS[(size_t)(g*16 + pos)*VCH + khalf*8];
        acc[mi][gi] = __builtin_amdgcn_mfma_f32_16x16x32_bf16(a, bf, acc[mi][gi], 0,0,0);
      }
    }
    __syncthreads();
  }

  // epilogue: wave w writes row gy0+w (both 16-px halves, nt)
  float* ob = out + ((size_t)z*NB + b)*(size_t)C*NPIX;
  const int gy = gy0 + w;
  #pragma unroll
  for (int mi = 0; mi < 6; ++mi){
    #pragma unroll
    for (int r = 0; r < 4; ++r){
      float* base = &ob[(size_t)(mi*16 + khalf*4 + r)*NPIX + (size_t)gy*WW + gx0 + pos];
      __builtin_nontemporal_store(acc[mi][0][r], base);
      __builtin_nontemporal_store(acc[mi][1][r], base + 16);
    }
  }
}

// ============================ fallback (r4) kernels (row-major xt) ============================
__device__ __forceinline__ void conv48c(
  const unsigned short* __restrict__ xbase, const float* __restrict__ wmat,
  const float* __restrict__ bias, int row0,
  int gx0, int gy0, int lane, int w, unsigned short* __restrict__ Ysh)
{
  const int hy = lane & 15, khalf = lane >> 4;
  const int gy = gy0 - 1 + hy;
  short8 xf[3][3]; bool imv[3]; int np = (w < 2) ? 3 : 2;
  #pragma unroll
  for (int i = 0; i < 3; ++i){
    if (i >= np) break;
    int pt = w + i*8;
    int gx = gx0 - 1 + pt;
    bool im = (gx>=0) && (gx<WW) && (gy>=0) && (gy<HH);
    imv[i] = im;
    int n = im ? (gy*WW + gx) : 0;
    const unsigned short* xp = xbase + (size_t)n*96 + khalf*8;
    short8 z = {};
    #pragma unroll
    for (int kk = 0; kk < 3; ++kk){
      short8 v = *(const short8*)(xp + kk*32);
      xf[i][kk] = im ? v : z;
    }
  }
  #pragma unroll 1
  for (int mi = 0; mi < 3; ++mi){
    int orow = row0 + mi*16 + hy;
    const float* wp = wmat + (size_t)orow*96 + khalf*8;
    short8 a0 = pack8(*(const float4*)(wp),    *(const float4*)(wp+4));
    short8 a1 = pack8(*(const float4*)(wp+32), *(const float4*)(wp+36));
    short8 a2 = pack8(*(const float4*)(wp+64), *(const float4*)(wp+68));
    float4 bv = *(const float4*)&bias[row0 + mi*16 + khalf*4];
    #pragma unroll
    for (int i = 0; i < 3; ++i){
      if (i >= np) break;
      int pt = w + i*8;
      f32x4 acc = {bv.x, bv.y, bv.z, bv.w};
      acc = __builtin_amdgcn_mfma_f32_16x16x32_bf16(a0, xf[i][0], acc, 0,0,0);
      acc = __builtin_amdgcn_mfma_f32_16x16x32_bf16(a1, xf[i][1], acc, 0,0,0);
      acc = __builtin_amdgcn_mfma_f32_16x16x32_bf16(a2, xf[i][2], acc, 0,0,0);
      #pragma unroll
      for (int r = 0; r < 4; ++r){
        int ch = mi*16 + khalf*4 + r;
        Ysh[ch*YP + pt*16 + hy] = imv[i] ? f2b(acc[r]) : (unsigned short)0;
      }
    }
  }
}

__global__ __launch_bounds__(512, 4) void kqk(
  const unsigned short* __restrict__ xt,
  const float* __restrict__ q_w, const float* __restrict__ q_b,
  const float* __restrict__ qd_w, const float* __restrict__ qd_b,
  const float* __restrict__ kv_w, const float* __restrict__ kv_b,
  const float* __restrict__ kvd_w, const float* __restrict__ kvd_b,
  float* __restrict__ pg, float* __restrict__ psq)
{
  __shared__ unsigned short Ysh[48*YP];
  __shared__ unsigned short qS[48*QP];
  __shared__ unsigned short kT[48*QP];
  __shared__ float redq[C], redk[C];

  const int t = threadIdx.x, lane = t & 63, w = t >> 6;
  const int b = blockIdx.y, tile = blockIdx.x;
  const int txx = tile & 15, tyy = tile >> 4;
  const int gx0 = txx*16, gy0 = tyy*14;
  if (t < C){ redq[t] = 0.f; redk[t] = 0.f; }
  __syncthreads();

  const unsigned short* xc = xt + ((size_t)(0*NB + b))*NPIX*96;
  const unsigned short* xs = xt + ((size_t)(1*NB + b))*NPIX*96;

  auto dwQK = [&](const float* dww, const float* dwb, int wrow0,
                  unsigned short* dst, float* red){
    for (int slot = t; slot < 48*16; slot += 512){
      int c = slot >> 4, j = slot & 15;
      const unsigned short* yb = &Ysh[c*YP + j*16];
      float u0[16], u1[16], u2[16];
      {
        short8 s0 = *(const short8*)(yb);
        short8 s1 = *(const short8*)(yb+8);
        short8 s2 = *(const short8*)(yb+16), s3 = *(const short8*)(yb+24);
        short8 s4 = *(const short8*)(yb+32), s5 = *(const short8*)(yb+40);
        #pragma unroll
        for (int u = 0; u < 8; ++u){
          u0[u]=b2f((unsigned short)s0[u]); u0[u+8]=b2f((unsigned short)s1[u]);
          u1[u]=b2f((unsigned short)s2[u]); u1[u+8]=b2f((unsigned short)s3[u]);
          u2[u]=b2f((unsigned short)s4[u]); u2[u+8]=b2f((unsigned short)s5[u]);
        }
      }
      const float* wd = dww + (size_t)(wrow0 + c)*9;
      float w00=wd[0],w01=wd[1],w02=wd[2],w10=wd[3],w11=wd[4],w12=wd[5],w20=wd[6],w21=wd[7],w22=wd[8];
      float bb = dwb[wrow0 + c];
      unsigned short vv[16];
      float sq = 0.f;
      #pragma unroll
      for (int py = 0; py < 14; ++py){
        float s = bb;
        s = fmaf(w00,u0[py],s); s = fmaf(w10,u0[py+1],s); s = fmaf(w20,u0[py+2],s);
        s = fmaf(w01,u1[py],s); s = fmaf(w11,u1[py+1],s); s = fmaf(w21,u1[py+2],s);
        s = fmaf(w02,u2[py],s); s = fmaf(w12,u2[py+1],s); s = fmaf(w22,u2[py+2],s);
        if (gy0 + py >= HH) s = 0.f;
        sq = fmaf(s, s, sq);
        vv[py] = f2b(s);
      }
      vv[14] = 0; vv[15] = 0;
      atomicAdd(&red[wrow0 + c], sq);
      *(short8*)&dst[c*QP + j*16]     = *(short8*)&vv[0];
      *(short8*)&dst[c*QP + j*16 + 8] = *(short8*)&vv[8];
    }
  };

  auto gram = [&](int cc){
    int hl = w & 1, slice = w >> 1;
    int cl = lane & 31; bool cv = cl < CH;
    int row = hl*CH + (cv ? cl : 0);
    f32x16 g;
    #pragma unroll
    for (int r = 0; r < 16; ++r) g[r] = 0.f;
    short8 z = {};
    for (int ks = slice; ks < 16; ks += 4){
      int ko = ks*16 + (lane>>5)*8;
      short8 qa = *(const short8*)&qS[row*QP + ko];
      short8 kb = *(const short8*)&kT[row*QP + ko];
      if (!cv){ qa = z; kb = z; }
      g = __builtin_amdgcn_mfma_f32_32x32x16_bf16(qa, kb, g, 0,0,0);
    }
    float* stg = (float*)Ysh;
    if (slice != 0){
      float* dst = stg + (size_t)(hl*3 + slice - 1)*1024;
      #pragma unroll
      for (int r = 0; r < 16; ++r) dst[r*64 + lane] = g[r];
    }
    __syncthreads();
    if (slice == 0){
      const float* s0 = stg + (size_t)(hl*3 + 0)*1024;
      const float* s1 = stg + (size_t)(hl*3 + 1)*1024;
      const float* s2 = stg + (size_t)(hl*3 + 2)*1024;
      float* dst = pg + ((size_t)(tile*NB + b)*HEADS + cc*2 + hl)*1024;
      #pragma unroll
      for (int r = 0; r < 16; ++r){
        int ix = r*64 + lane;
        dst[ix] = g[r] + s0[ix] + s1[ix] + s2[ix];
      }
    }
  };

  #pragma unroll 1
  for (int cc = 0; cc < 2; ++cc){
    conv48c(xc, q_w, q_b, cc*48, gx0, gy0, lane, w, Ysh);
    __syncthreads();
    dwQK(qd_w, qd_b, cc*48, qS, redq);
    __syncthreads();
    conv48c(xs, kv_w, kv_b, cc*48, gx0, gy0, lane, w, Ysh);
    __syncthreads();
    dwQK(kvd_w, kvd_b, cc*48, kT, redk);
    __syncthreads();
    gram(cc);
    __syncthreads();
  }
  if (t < 192){
    float v = (t < 96) ? redq[t] : redk[t - 96];
    psq[(size_t)(tile*NB + b)*192 + t] = v;
  }
}

__global__ __launch_bounds__(256) void kgredF(
  const float* __restrict__ pg, const float* __restrict__ psq, float* __restrict__ ws)
{
  const int bh = blockIdx.x;
  const int b = bh >> 2, h = bh & 3;
  const int t = threadIdx.x;
  float a0=0.f, a1=0.f, a2=0.f, a3=0.f, sq=0.f;
  for (int tile = 0; tile < NTILES; ++tile){
    const float* p = pg + ((size_t)(tile*NB + b)*HEADS + h)*1024;
    a0 += p[t]; a1 += p[t+256]; a2 += p[t+512]; a3 += p[t+768];
    if (t < 48){
      int ch = h*CH + (t % CH);
      sq += psq[(size_t)(tile*NB + b)*192 + (t < CH ? ch : 96 + ch)];
    }
  }
  if (t < 48){
    if (t < CH) ws[WS_SUMSQ_Q + b*C + h*CH + t] = sq;
    else        ws[WS_SUMSQ_K + b*C + h*CH + (t - CH)] = sq;
  }
  float accs[4] = {a0, a1, a2, a3};
  #pragma unroll
  for (int i = 0; i < 4; ++i){
    int idx = i*256 + t;
    int r = idx >> 6, ln = idx & 63;
    int row = (r&3) + 8*(r>>2) + 4*(ln>>5);
    int col = ln & 31;
    if (row < CH && col < CH)
      ws[WS_GRAM + ((size_t)(b*HEADS + h)*CH + row)*CH + col] = accs[i];
  }
}

__global__ __launch_bounds__(512, 4) void kv_out(
  const unsigned short* __restrict__ xs,
  const float* __restrict__ kv_w, const float* __restrict__ kv_b,
  const float* __restrict__ kvd_w, const float* __restrict__ kvd_b,
  const float* __restrict__ ps_b, const float* __restrict__ psh_b,
  const unsigned short* __restrict__ mb, float* __restrict__ out)
{
  __shared__ unsigned short Ysh[48*YP];
  __shared__ unsigned short vS2[224*VP];
  const int t = threadIdx.x, lane = t & 63, w = t >> 6;
  const int b = blockIdx.y, tile = blockIdx.x;
  const int txx = tile & 15, tyy = tile >> 4;
  const int gx0 = txx*16, gy0 = tyy*14;
  const unsigned short* xb_ = xs + (size_t)b*NPIX*96;

  #pragma unroll 1
  for (int which = 0; which < 2; ++which){
    #pragma unroll 1
    for (int cv = 0; cv < 2; ++cv){
      int row0 = 96 + which*96 + cv*48;
      conv48c(xb_, kv_w, kv_b, row0, gx0, gy0, lane, w, Ysh);
      __syncthreads();
      for (int slot = t; slot < 48*16; slot += 512){
        int c = slot >> 4, j = slot & 15;
        const unsigned short* yb = &Ysh[c*YP + j*16];
        float u0[16], u1[16], u2[16];
        {
          short8 s0 = *(const short8*)(yb),    s1 = *(const short8*)(yb+8);
          short8 s2 = *(const short8*)(yb+16), s3 = *(const short8*)(yb+24);
          short8 s4 = *(const short8*)(yb+32), s5 = *(const short8*)(yb+40);
          #pragma unroll
          for (int u = 0; u < 8; ++u){
            u0[u]=b2f((unsigned short)s0[u]); u0[u+8]=b2f((unsigned short)s1[u]);
            u1[u]=b2f((unsigned short)s2[u]); u1[u+8]=b2f((unsigned short)s3[u]);
            u2[u]=b2f((unsigned short)s4[u]); u2[u+8]=b2f((unsigned short)s5[u]);
          }
        }
        const float* wd = kvd_w + (size_t)(row0 + c)*9;
        float w00=wd[0],w01=wd[1],w02=wd[2],w10=wd[3],w11=wd[4],w12=wd[5],w20=wd[6],w21=wd[7],w22=wd[8];
        float bb = kvd_b[row0 + c];
        #pragma unroll
        for (int py = 0; py < 14; ++py){
          float s = bb;
          s = fmaf(w00,u0[py],s); s = fmaf(w10,u0[py+1],s); s = fmaf(w20,u0[py+2],s);
          s = fmaf(w01,u1[py],s); s = fmaf(w11,u1[py+1],s); s = fmaf(w21,u1[py+2],s);
          s = fmaf(w02,u2[py],s); s = fmaf(w12,u2[py+1],s); s = fmaf(w22,u2[py+2],s);
          vS2[(py*16 + j)*VP + cv*48 + c] = f2b(s);
        }
      }
      __syncthreads();
    }
    const unsigned short* mbp = mb + ((size_t)which*NB + b)*9216;
    const float* bias = which ? psh_b : ps_b;
    float* ob = out + (size_t)which*NB*C*NPIX + (size_t)b*C*NPIX;
    for (int tl = w; tl < 84; tl += 8){
      int mi = tl / 14, n = tl - mi*14;
      const unsigned short* mp = mbp + (size_t)(mi*16 + (lane&15))*96 + (lane>>4)*8;
      short8 a0 = *(const short8*)(mp);
      short8 a1 = *(const short8*)(mp + 32);
      short8 a2 = *(const short8*)(mp + 64);
      float4 bv = *(const float4*)&bias[mi*16 + (lane>>4)*4];
      f32x4 acc = {bv.x, bv.y, bv.z, bv.w};
      const unsigned short* xb = &vS2[(size_t)(n*16 + (lane&15))*VP + (lane>>4)*8];
      acc = __builtin_amdgcn_mfma_f32_16x16x32_bf16(a0, *(const short8*)(xb),    acc, 0,0,0);
      acc = __builtin_amdgcn_mfma_f32_16x16x32_bf16(a1, *(const short8*)(xb+32), acc, 0,0,0);
      acc = __builtin_amdgcn_mfma_f32_16x16x32_bf16(a2, *(const short8*)(xb+64), acc, 0,0,0);
      int gy = gy0 + n;
      if (gy < HH){
        #pragma unroll
        for (int r = 0; r < 4; ++r)
          ob[(size_t)(mi*16 + (lane>>4)*4 + r)*NPIX + gy*WW + gx0 + (lane&15)] = acc[r];
      }
    }
    __syncthreads();
  }
}

extern "C" void kernel_launch(void* const* d_in, const int* in_sizes, int n_in,
                              void* d_out, int out_size, void* d_ws, size_t ws_size,
                              hipStream_t stream)
{
  const float* content = (const float*)d_in[0];
  const float* style   = (const float*)d_in[1];
  const float* temp    = (const float*)d_in[2];
  const float* q_w   = (const float*)d_in[3];
  const float* q_b   = (const float*)d_in[4];
  const float* qd_w  = (const float*)d_in[5];
  const float* qd_b  = (const float*)d_in[6];
  const float* kv_w  = (const float*)d_in[7];
  const float* kv_b  = (const float*)d_in[8];
  const float* kvd_w = (const float*)d_in[9];
  const float* kvd_b = (const float*)d_in[10];
  const float* ps_w  = (const float*)d_in[11];
  const float* ps_b  = (const float*)d_in[12];
  const float* psh_w = (const float*)d_in[13];
  const float* psh_b = (const float*)d_in[14];
  float* out = (float*)d_out;
  float* ws  = (float*)d_ws;

  unsigned short* xt = (unsigned short*)((char*)d_ws + XT_OFF_BYTES);

  if (ws_size >= WS_NEED3){
    unsigned short* qk  = (unsigned short*)((char*)d_ws + QK_OFF);
    float* pg  = (float*)((char*)d_ws + PG_OFF);
    float* psq = (float*)((char*)d_ws + PSQ_OFF);
    unsigned short* mb = (unsigned short*)((char*)d_ws + MB_OFF);
    unsigned short* wb = (unsigned short*)((char*)d_ws + WB_OFF);

    k0t<<<dim3(NPIX/64, NB, 2), dim3(256), 0, stream>>>(content, style, xt, 1);
    kwpack<<<dim3(144), dim3(256), 0, stream>>>(q_w, kv_w, wb);
    kconv<<<dim3(NTILES, NB, 4), dim3(512), 0, stream>>>(
        xt, wb, q_b, qd_w, qd_b, kv_b, kvd_w, kvd_b, qk, psq);
    kgram<<<dim3(KSPLIT, NB), dim3(384), 0, stream>>>(qk, pg);
    kgredN<<<dim3(NB, 37), dim3(256), 0, stream>>>(pg, psq, ws);
    k2_attn<<<dim3(NB), dim3(256), 0, stream>>>(temp, ps_w, psh_w, ws, mb);
    kvm<<<dim3(NTV2, NB, 2), dim3(512), 0, stream>>>(
        xt, wb, kv_b, kvd_w, kvd_b, mb, ps_b, psh_b, out);
  } else {
    float* pg  = (float*)((char*)d_ws + F_PG_OFF);
    float* psq = (float*)((char*)d_ws + F_PSQ_OFF);
    unsigned short* mb = (unsigned short*)((char*)d_ws + F_MB_OFF);
    k0t<<<dim3(NPIX/64, NB, 2), dim3(256), 0, stream>>>(content, style, xt, 0);
    kqk<<<dim3(NTILES, NB), dim3(512), 0, stream>>>(
        xt, q_w, q_b, qd_w, qd_b, kv_w, kv_b, kvd_w, kvd_b, pg, psq);
    kgredF<<<dim3(NB*HEADS), dim3(256), 0, stream>>>(pg, psq, ws);
    k2_attn<<<dim3(NB), dim3(256), 0, stream>>>(temp, ps_w, psh_w, ws, mb);
    kv_out<<<dim3(NTILES, NB), dim3(512), 0, stream>>>(
        xt + (size_t)NB*NPIX*96, kv_w, kv_b, kvd_w, kvd_b, ps_b, psh_b, mb, out);
  }
}